// Round 9
// baseline (187.328 us; speedup 1.0000x reference)
//
#include <hip/hip_runtime.h>
#include <hip/hip_bf16.h>
#include <stdint.h>

typedef __attribute__((ext_vector_type(8))) short bf16x8;
typedef __attribute__((ext_vector_type(4))) float f32x4;

#define NB 8192

__device__ __forceinline__ unsigned pkbf(float x, float y) {
    __hip_bfloat162 h = __float22bfloat162_rn(make_float2(x, y));  // v_cvt_pk_bf16_f32 (RNE)
    unsigned r;
    __builtin_memcpy(&r, &h, 4);
    return r;
}

__device__ __forceinline__ uint4 pack8(float4 a, float4 b) {
    uint4 r;
    r.x = pkbf(a.x, a.y);
    r.y = pkbf(a.z, a.w);
    r.z = pkbf(b.x, b.y);
    r.w = pkbf(b.z, b.w);
    return r;
}

__device__ __forceinline__ void keepf(float v) { asm volatile("" :: "v"(v)); }

// ---------------------------------------------------------------------------
// prep: W[512][2048] fp32 -> bf16, fragment-linear layout for MFMA B-operand.
// ---------------------------------------------------------------------------
__global__ __launch_bounds__(256)
void prep_w_kernel(const float* __restrict__ W, uint4* __restrict__ Wt) {
    int t = blockIdx.x * 256 + threadIdx.x;   // 0..65535
    int lane = t & 63;
    int frag = t >> 6;                         // kb*32 + cb
    int kb = frag >> 5, cb = frag & 31;
    int o = cb * 16 + (lane & 15);
    int k = kb * 32 + ((lane >> 4) << 3);
    const float* src = W + (size_t)o * 2048 + k;
    float4 a = *(const float4*)src;
    float4 b = *(const float4*)(src + 4);
    Wt[t] = pack8(a, b);
}

// ---------------------------------------------------------------------------
// score kernel v8 (UNCHANGED from round 8 -- this round is diagnostic).
// ---------------------------------------------------------------------------
template<int MFN, int DN>
__device__ __forceinline__ void score_body(
        const float* __restrict__ xp, int node, int m0,
        const float* __restrict__ bias, const float* __restrict__ hvec,
        const uint4* __restrict__ Wt, float* __restrict__ scores,
        uint4* lA, float* red) {
    constexpr int BM = MFN * 16;
    constexpr int NKB = DN / 32;
    int t = threadIdx.x;
    int l = t & 63;
    int w = t >> 6;

#pragma unroll
    for (int j = 0; j < 16; ++j) {
        int f = (t >> 6) + j * 8;
        int kb = f / MFN, mf = f % MFN;
        int row = mf * 16 + (l & 15);
        int k = kb * 32 + ((l >> 4) << 3);
        const float* g = xp + (size_t)(m0 + row) * DN + k;
        float4 a = *(const float4*)g;
        float4 b = *(const float4*)(g + 4);
        lA[f * 64 + l] = pack8(a, b);
    }
    __syncthreads();

    f32x4 acc[MFN][4];
#pragma unroll
    for (int mf = 0; mf < MFN; ++mf)
#pragma unroll
        for (int nf = 0; nf < 4; ++nf)
            acc[mf][nf] = (f32x4){0.f, 0.f, 0.f, 0.f};

    bf16x8 bcur[4];
    {
        const uint4* wp = Wt + ((0 + (w << 2)) << 6) + l;
#pragma unroll
        for (int nf = 0; nf < 4; ++nf) {
            uint4 u = wp[nf << 6];
            __builtin_memcpy(&bcur[nf], &u, 16);
        }
    }
    for (int kb = 0; kb < NKB; ++kb) {
        bf16x8 bnxt[4];
        if (kb + 1 < NKB) {
            const uint4* wp = Wt + ((((kb + 1) << 5) + (w << 2)) << 6) + l;
#pragma unroll
            for (int nf = 0; nf < 4; ++nf) {
                uint4 u = wp[nf << 6];
                __builtin_memcpy(&bnxt[nf], &u, 16);
            }
        }
#pragma unroll
        for (int mf = 0; mf < MFN; ++mf) {
            uint4 u = lA[(kb * MFN + mf) * 64 + l];
            bf16x8 afr;
            __builtin_memcpy(&afr, &u, 16);
#pragma unroll
            for (int nf = 0; nf < 4; ++nf)
                acc[mf][nf] = __builtin_amdgcn_mfma_f32_16x16x32_bf16(
                    afr, bcur[nf], acc[mf][nf], 0, 0, 0);
        }
#pragma unroll
        for (int nf = 0; nf < 4; ++nf) bcur[nf] = bnxt[nf];
    }

    float bv[4], hv[4];
#pragma unroll
    for (int nf = 0; nf < 4; ++nf) {
        int o = (w << 6) + (nf << 4) + (l & 15);
        bv[nf] = bias[o];
        hv[nf] = hvec[o];
    }
#pragma unroll
    for (int mf = 0; mf < MFN; ++mf) {
        float sc[4] = {0.f, 0.f, 0.f, 0.f};
#pragma unroll
        for (int nf = 0; nf < 4; ++nf) {
#pragma unroll
            for (int r = 0; r < 4; ++r) {
                float xv = acc[mf][nf][r] + bv[nf];
                float th = 1.f - 2.f * __builtin_amdgcn_rcpf(1.f + __expf(2.f * xv));
                sc[r] = fmaf(hv[nf], th, sc[r]);
            }
        }
#pragma unroll
        for (int r = 0; r < 4; ++r) {
            float v = sc[r];
            v += __shfl_xor(v, 1);
            v += __shfl_xor(v, 2);
            v += __shfl_xor(v, 4);
            v += __shfl_xor(v, 8);
            if ((l & 15) == 0)
                red[w * BM + (mf << 4) + ((l >> 4) << 2) + r] = v;
        }
    }
    __syncthreads();
    if (t < BM) {
        float ssum = 0.f;
#pragma unroll
        for (int w2 = 0; w2 < 8; ++w2) ssum += red[w2 * BM + t];
        scores[node * NB + m0 + t] = ssum;
    }
}

__global__ __launch_bounds__(512, 2)
void score_kernel(const float* __restrict__ x0, const float* __restrict__ x1,
                  const float* __restrict__ x2, const float* __restrict__ x3,
                  const float* __restrict__ x4, const float* __restrict__ x5,
                  const float* __restrict__ bias, const float* __restrict__ hvec,
                  const uint4* __restrict__ Wt, float* __restrict__ scores) {
    __shared__ uint4 lA[8192];        // 128 KB A panel
    __shared__ float red[8 * 128];

    int bid = blockIdx.x;
    if (bid < 256) {
        const float* xp = (bid & 1) ? x4 : x0;
        int node = (bid & 1) ? 4 : 0;
        int m0 = (bid >> 1) * 64;
        score_body<4, 1024>(xp, node, m0, bias, hvec, Wt, scores, lA, red);
    } else {
        int lb = bid - 256;
        int ni = lb & 3;
        const float* xp = (ni == 0) ? x1 : (ni == 1) ? x2 : (ni == 2) ? x3 : x5;
        int node = (ni == 0) ? 1 : (ni == 1) ? 2 : (ni == 2) ? 3 : 5;
        int m0 = (lb >> 2) * 128;
        score_body<8, 512>(xp, node, m0, bias, hvec, Wt, scores, lA, red);
    }
}

// ---------------------------------------------------------------------------
// ABLATION kernels (diagnostic; write nothing; rule-17 keepalives).
// VAR=1 noB   : A staging + ds_read + MFMA (B const)
// VAR=2 noA   : B L2 loads + MFMA (A const; no staging/LDS traffic)
// VAR=3 mfma  : MFMA only (both const)
// VAR=4 mem   : A staging + ds_read + B loads, NO MFMA (xor-fold keepalive)
// Same 512-block grid + same 128KB LDS allocation as the real kernel so the
// occupancy regime matches (LDS kept allocated via dummy write).
// ---------------------------------------------------------------------------
template<int MFN, int DN, int VAR>
__device__ __forceinline__ void abl_body(const float* __restrict__ xp, int m0,
                                         const uint4* __restrict__ Wt, uint4* lA) {
    constexpr int NKB = DN / 32;
    int t = threadIdx.x;
    int l = t & 63;
    int w = t >> 6;

    if constexpr (VAR == 1 || VAR == 4) {
#pragma unroll
        for (int j = 0; j < 16; ++j) {
            int f = (t >> 6) + j * 8;
            int kb = f / MFN, mf = f % MFN;
            int row = mf * 16 + (l & 15);
            int k = kb * 32 + ((l >> 4) << 3);
            const float* g = xp + (size_t)(m0 + row) * DN + k;
            float4 a = *(const float4*)g;
            float4 b = *(const float4*)(g + 4);
            lA[f * 64 + l] = pack8(a, b);
        }
    } else {
        if (t == 0) lA[0] = make_uint4(1u, 2u, 3u, 4u);  // keep LDS allocated
    }
    __syncthreads();

    f32x4 acc[MFN][4];
#pragma unroll
    for (int mf = 0; mf < MFN; ++mf)
#pragma unroll
        for (int nf = 0; nf < 4; ++nf)
            acc[mf][nf] = (f32x4){0.f, 0.f, 0.f, 0.f};

    bf16x8 cA, cB;
    {
        uint4 one = make_uint4(0x3f803f80u, 0x3f803f80u, 0x3f803f80u, 0x3f803f80u);
        __builtin_memcpy(&cA, &one, 16);
        __builtin_memcpy(&cB, &one, 16);
    }
    unsigned fold = 0;

    bf16x8 bcur[4];
    if constexpr (VAR == 2 || VAR == 4) {
        const uint4* wp = Wt + ((0 + (w << 2)) << 6) + l;
#pragma unroll
        for (int nf = 0; nf < 4; ++nf) {
            uint4 u = wp[nf << 6];
            __builtin_memcpy(&bcur[nf], &u, 16);
        }
    }
    for (int kb = 0; kb < NKB; ++kb) {
        bf16x8 bnxt[4];
        if constexpr (VAR == 2 || VAR == 4) {
            if (kb + 1 < NKB) {
                const uint4* wp = Wt + ((((kb + 1) << 5) + (w << 2)) << 6) + l;
#pragma unroll
                for (int nf = 0; nf < 4; ++nf) {
                    uint4 u = wp[nf << 6];
                    __builtin_memcpy(&bnxt[nf], &u, 16);
                }
            }
        }
#pragma unroll
        for (int mf = 0; mf < MFN; ++mf) {
            bf16x8 afr;
            if constexpr (VAR == 1 || VAR == 4) {
                uint4 u = lA[(kb * MFN + mf) * 64 + l];
                __builtin_memcpy(&afr, &u, 16);
            } else {
                afr = cA;
            }
            if constexpr (VAR == 4) {
                uint4 u;
                __builtin_memcpy(&u, &afr, 16);
                fold ^= u.x ^ u.w;
            } else {
#pragma unroll
                for (int nf = 0; nf < 4; ++nf) {
                    bf16x8 bop;
                    if constexpr (VAR == 2) bop = bcur[nf]; else bop = cB;
                    acc[mf][nf] = __builtin_amdgcn_mfma_f32_16x16x32_bf16(
                        afr, bop, acc[mf][nf], 0, 0, 0);
                }
            }
        }
        if constexpr (VAR == 2 || VAR == 4) {
            if constexpr (VAR == 4) {
#pragma unroll
                for (int nf = 0; nf < 4; ++nf) {
                    uint4 u;
                    __builtin_memcpy(&u, &bnxt[nf], 16);
                    fold ^= u.x;
                }
            }
#pragma unroll
            for (int nf = 0; nf < 4; ++nf) bcur[nf] = bnxt[nf];
        }
    }
    if constexpr (VAR == 4) {
        keepf(__uint_as_float(fold));
    } else {
        float s = 0.f;
#pragma unroll
        for (int mf = 0; mf < MFN; ++mf)
#pragma unroll
            for (int nf = 0; nf < 4; ++nf)
#pragma unroll
                for (int r = 0; r < 4; ++r) s += acc[mf][nf][r];
        keepf(s);
    }
}

template<int VAR>
__global__ __launch_bounds__(512, 2)
void score_abl(const float* __restrict__ x0, const float* __restrict__ x1,
               const float* __restrict__ x2, const float* __restrict__ x3,
               const float* __restrict__ x4, const float* __restrict__ x5,
               const uint4* __restrict__ Wt) {
    __shared__ uint4 lA[8192];        // 128 KB, same as real kernel
    int bid = blockIdx.x;
    if (bid < 256) {
        const float* xp = (bid & 1) ? x4 : x0;
        int m0 = (bid >> 1) * 64;
        abl_body<4, 1024, VAR>(xp, m0, Wt, lA);
    } else {
        int lb = bid - 256;
        int ni = lb & 3;
        const float* xp = (ni == 0) ? x1 : (ni == 1) ? x2 : (ni == 2) ? x3 : x5;
        int m0 = (lb >> 2) * 128;
        abl_body<8, 512, VAR>(xp, m0, Wt, lA);
    }
}

// ---------------------------------------------------------------------------
// z kernel (unchanged)
// ---------------------------------------------------------------------------
__global__ __launch_bounds__(256)
void z_kernel(const float* __restrict__ x0, const float* __restrict__ x1,
              const float* __restrict__ x2, const float* __restrict__ x3,
              const float* __restrict__ x4, const float* __restrict__ x5,
              const float* __restrict__ scores, float* __restrict__ out) {
    int wv = threadIdx.x >> 6;
    int lane = threadIdx.x & 63;
    int b = (blockIdx.x << 2) + wv;

    float s0 = scores[b];
    float s1 = scores[NB + b];
    float s2 = scores[2 * NB + b];
    float s3 = scores[3 * NB + b];
    float s4 = scores[4 * NB + b];
    float s5 = scores[5 * NB + b];
    float m = fmaxf(fmaxf(fmaxf(s0, s1), fmaxf(s2, s3)), fmaxf(s4, s5));
    float e0 = __expf(s0 - m), e1 = __expf(s1 - m), e2 = __expf(s2 - m);
    float e3 = __expf(s3 - m), e4 = __expf(s4 - m), e5 = __expf(s5 - m);
    float inv = __builtin_amdgcn_rcpf(e0 + e1 + e2 + e3 + e4 + e5);
    float b0 = e0 * inv, b1 = e1 * inv, b2 = e2 * inv;
    float b3 = e3 * inv, b4 = e4 * inv, b5 = e5 * inv;

    const float* pls = x0 + (size_t)b * 1024;
    const float* pA  = x1 + (size_t)b * 512;
    const float* plm = x2 + (size_t)b * 512;
    const float* pAT = x3 + (size_t)b * 512;
    const float* pds = x4 + (size_t)b * 1024;
    const float* pdm = x5 + (size_t)b * 512;
    float* po = out + (size_t)b * 2048;

#pragma unroll
    for (int j = 0; j < 2; ++j) {
        int c = (j << 8) + (lane << 2);
        float4 vls = *(const float4*)(pls + c);
        float4 vA  = *(const float4*)(pA + c);
        float4 vlm = *(const float4*)(plm + c);
        float4 vAT = *(const float4*)(pAT + c);
        float4 vds = *(const float4*)(pds + c);
        float4 vdm = *(const float4*)(pdm + c);
        float4 r;
        r.x = b0*vls.x + b1*vA.x + b2*vlm.x + b3*vAT.x + b4*vds.x + b5*vdm.x;
        r.y = b0*vls.y + b1*vA.y + b2*vlm.y + b3*vAT.y + b4*vds.y + b5*vdm.y;
        r.z = b0*vls.z + b1*vA.z + b2*vlm.z + b3*vAT.z + b4*vds.z + b5*vdm.z;
        r.w = b0*vls.w + b1*vA.w + b2*vlm.w + b3*vAT.w + b4*vds.w + b5*vdm.w;
        *(float4*)(po + c) = r;
    }
#pragma unroll
    for (int j = 0; j < 2; ++j) {
        int c = 512 + (j << 8) + (lane << 2);
        float4 vls = *(const float4*)(pls + c);
        float4 vds = *(const float4*)(pds + c);
        float4 r;
        r.x = b0*vls.x + b4*vds.x;
        r.y = b0*vls.y + b4*vds.y;
        r.z = b0*vls.z + b4*vds.z;
        r.w = b0*vls.w + b4*vds.w;
        *(float4*)(po + c) = r;
    }
    float4 zz = make_float4(0.f, 0.f, 0.f, 0.f);
#pragma unroll
    for (int j = 0; j < 4; ++j) {
        int c = 1024 + (j << 8) + (lane << 2);
        *(float4*)(po + c) = zz;
    }
}

extern "C" void kernel_launch(void* const* d_in, const int* in_sizes, int n_in,
                              void* d_out, int out_size, void* d_ws, size_t ws_size,
                              hipStream_t stream) {
    const float* x0   = (const float*)d_in[0];  // ls  [8192,1024]
    const float* x1   = (const float*)d_in[1];  // A   [8192,512]
    const float* x2   = (const float*)d_in[2];  // lm  [8192,512]
    const float* x3   = (const float*)d_in[3];  // AT  [8192,512]
    const float* x4   = (const float*)d_in[4];  // ds  [8192,1024]
    const float* x5   = (const float*)d_in[5];  // dm  [8192,512]
    const float* W    = (const float*)d_in[6];  // [512,2048]
    const float* bias = (const float*)d_in[7];  // [512]
    const float* hvec = (const float*)d_in[8];  // [512,1]

    uint4* Wt = (uint4*)d_ws;                              // 1 MB
    float* scores = (float*)((char*)d_ws + (1u << 20));    // 192 KB

    prep_w_kernel<<<256, 256, 0, stream>>>(W, Wt);
    score_kernel<<<512, 512, 0, stream>>>(x0, x1, x2, x3, x4, x5, bias, hvec, Wt, scores);
    z_kernel<<<2048, 256, 0, stream>>>(x0, x1, x2, x3, x4, x5, scores, (float*)d_out);

    // ---- diagnostic ablations (no effect on d_out) ----
    score_abl<1><<<512, 512, 0, stream>>>(x0, x1, x2, x3, x4, x5, Wt);  // noB
    score_abl<2><<<512, 512, 0, stream>>>(x0, x1, x2, x3, x4, x5, Wt);  // noA
    score_abl<3><<<512, 512, 0, stream>>>(x0, x1, x2, x3, x4, x5, Wt);  // mfma-only
    score_abl<4><<<512, 512, 0, stream>>>(x0, x1, x2, x3, x4, x5, Wt);  // mem-only
}

// Round 10
// 131.334 us; speedup vs baseline: 1.4263x; 1.4263x over previous
//
#include <hip/hip_runtime.h>
#include <hip/hip_bf16.h>
#include <stdint.h>

typedef __attribute__((ext_vector_type(8))) short bf16x8;
typedef __attribute__((ext_vector_type(4))) float f32x4;

#define NB 8192

__device__ __forceinline__ unsigned pkbf(float x, float y) {
    __hip_bfloat162 h = __float22bfloat162_rn(make_float2(x, y));  // v_cvt_pk_bf16_f32 (RNE)
    unsigned r;
    __builtin_memcpy(&r, &h, 4);
    return r;
}

__device__ __forceinline__ uint4 pack8(float4 a, float4 b) {
    uint4 r;
    r.x = pkbf(a.x, a.y);
    r.y = pkbf(a.z, a.w);
    r.z = pkbf(b.x, b.y);
    r.w = pkbf(b.z, b.w);
    return r;
}

__device__ __forceinline__ void gload16(const uint4* g, void* l) {
    __builtin_amdgcn_global_load_lds(
        (const __attribute__((address_space(1))) void*)g,
        (__attribute__((address_space(3))) void*)l, 16, 0, 0);
}

// ---------------------------------------------------------------------------
// prep_w: W[512][2048] fp32 -> bf16 fragment-linear (B operand). Unchanged.
// ---------------------------------------------------------------------------
__global__ __launch_bounds__(256)
void prep_w_kernel(const float* __restrict__ W, uint4* __restrict__ Wt) {
    int t = blockIdx.x * 256 + threadIdx.x;
    int lane = t & 63;
    int frag = t >> 6;
    int kb = frag >> 5, cb = frag & 31;
    int o = cb * 16 + (lane & 15);
    int k = kb * 32 + ((lane >> 4) << 3);
    const float* src = W + (size_t)o * 2048 + k;
    Wt[t] = pack8(*(const float4*)src, *(const float4*)(src + 4));
}

// ---------------------------------------------------------------------------
// prep_a: all six X arrays fp32 -> bf16, fragment-linear per 64-row tile, so
// the score kernel can global_load_lds them with LINEAR dst and lane-linear
// reads (0 conflicts, 0 staging VALU). Chunk c (16B = bf16x8):
//   node by range; within node: tile = cn>>log2(cpt), cc = cn&(cpt-1),
//   f = cc>>6 (kb=f>>2, mf=f&3), l = cc&63,
//   elem j = X[tile*64 + mf*16 + (l&15)][kb*32 + (l>>4)*8 + j]
// Total 4M chunks = 64 MB. Pure streaming (z-kernel regime, >6 TB/s).
// ---------------------------------------------------------------------------
__global__ __launch_bounds__(256)
void prep_a_kernel(const float* __restrict__ x0, const float* __restrict__ x1,
                   const float* __restrict__ x2, const float* __restrict__ x3,
                   const float* __restrict__ x4, const float* __restrict__ x5,
                   uint4* __restrict__ A) {
    int c = blockIdx.x * 256 + threadIdx.x;       // 0 .. 4M-1
    int s = c >> 19;                               // 512K-chunk sector
    const float* xp; int dn, cn, cshift;
    if (s < 2)      { xp = x0; dn = 1024; cn = c;                 cshift = 13; }
    else if (s == 2){ xp = x1; dn = 512;  cn = c - (2 << 19);     cshift = 12; }
    else if (s == 3){ xp = x2; dn = 512;  cn = c - (3 << 19);     cshift = 12; }
    else if (s == 4){ xp = x3; dn = 512;  cn = c - (4 << 19);     cshift = 12; }
    else if (s < 7) { xp = x4; dn = 1024; cn = c - (5 << 19);     cshift = 13; }
    else            { xp = x5; dn = 512;  cn = c - (7 << 19);     cshift = 12; }
    int tile = cn >> cshift;
    int cc = cn & ((1 << cshift) - 1);
    int f = cc >> 6, l = cc & 63;
    int kb = f >> 2, mf = f & 3;
    int row = (tile << 6) + (mf << 4) + (l & 15);
    int k = (kb << 5) + ((l >> 4) << 3);
    const float* src = xp + (size_t)row * dn + k;
    A[c] = pack8(*(const float4*)src, *(const float4*)(src + 4));
}

// ---------------------------------------------------------------------------
// score v10: 768 blocks x 512 thr (8 waves). node=bid%6, tile=bid/6, BM=64,
// BN=512 (wave w: cols [w*64,+64)), acc[4][4]=64 AGPR.
// A panel arrives in 64KB k-halves via global_load_lds from the bf16 ws
// (NO staging VALU, NO staging registers). 3 barriers/block (heavy), k-loop
// barrier-free. LDS 66KB -> 2 blocks/CU; launch_bounds(512,4) targets 128
// combined regs -> 4 waves/SIMD: TLP covers L2-B + LDS latency (the r1-r9
// convoy had 2 waves/SIMD and serial fp32 reg-staging).
// ---------------------------------------------------------------------------
template<int DN>
__device__ __forceinline__ void score_v10_body(
        const uint4* __restrict__ an, int node, int tile,
        const float* __restrict__ bias, const float* __restrict__ hvec,
        const uint4* __restrict__ Wt, float* __restrict__ scores,
        uint4* lA, float* red) {
    constexpr int NKH = DN / 512;      // k-halves
    constexpr int CPT = DN * 8;        // chunks per 64-row tile
    int t = threadIdx.x;
    int l = t & 63;
    int w = t >> 6;

    f32x4 acc[4][4];
#pragma unroll
    for (int mf = 0; mf < 4; ++mf)
#pragma unroll
        for (int nf = 0; nf < 4; ++nf)
            acc[mf][nf] = (f32x4){0.f, 0.f, 0.f, 0.f};

    const uint4* tbase = an + (size_t)tile * CPT;

    for (int kh = 0; kh < NKH; ++kh) {
        if (kh > 0) __syncthreads();           // readers done with old half
        // stage 64KB half: 8 x gload16 per thread-wave slot, linear dst
        {
            const uint4* sb = tbase + (kh << 12) + (w << 9);
            char* db = (char*)lA + ((w << 9) << 4);
#pragma unroll
            for (int i = 0; i < 8; ++i)
                gload16(sb + (i << 6) + l, db + (i << 10));
        }
        __syncthreads();                        // drains DMA (vmcnt0) once/half

        for (int kbh = 0; kbh < 16; ++kbh) {
            int kb = (kh << 4) + kbh;
            const uint4* wp = Wt + (((kb << 5) + (w << 2)) << 6) + l;
            bf16x8 bfr[4];
#pragma unroll
            for (int nf = 0; nf < 4; ++nf) {
                uint4 u = wp[nf << 6];
                __builtin_memcpy(&bfr[nf], &u, 16);
            }
#pragma unroll
            for (int mf = 0; mf < 4; ++mf) {
                uint4 u = lA[(((kbh << 2) + mf) << 6) + l];
                bf16x8 afr;
                __builtin_memcpy(&afr, &u, 16);
#pragma unroll
                for (int nf = 0; nf < 4; ++nf)
                    acc[mf][nf] = __builtin_amdgcn_mfma_f32_16x16x32_bf16(
                        afr, bfr[nf], acc[mf][nf], 0, 0, 0);
            }
        }
    }

    // epilogue: tanh, dot with h, reduce
    float bv[4], hv[4];
#pragma unroll
    for (int nf = 0; nf < 4; ++nf) {
        int o = (w << 6) + (nf << 4) + (l & 15);
        bv[nf] = bias[o];
        hv[nf] = hvec[o];
    }
#pragma unroll
    for (int mf = 0; mf < 4; ++mf) {
        float sc[4] = {0.f, 0.f, 0.f, 0.f};
#pragma unroll
        for (int nf = 0; nf < 4; ++nf) {
#pragma unroll
            for (int r = 0; r < 4; ++r) {
                float xv = acc[mf][nf][r] + bv[nf];
                float th = 1.f - 2.f * __builtin_amdgcn_rcpf(1.f + __expf(2.f * xv));
                sc[r] = fmaf(hv[nf], th, sc[r]);
            }
        }
#pragma unroll
        for (int r = 0; r < 4; ++r) {
            float v = sc[r];
            v += __shfl_xor(v, 1);
            v += __shfl_xor(v, 2);
            v += __shfl_xor(v, 4);
            v += __shfl_xor(v, 8);
            if ((l & 15) == 0)
                red[(w << 6) + (mf << 4) + ((l >> 4) << 2) + r] = v;
        }
    }
    __syncthreads();
    if (t < 64) {
        float ssum = 0.f;
#pragma unroll
        for (int w2 = 0; w2 < 8; ++w2) ssum += red[(w2 << 6) + t];
        scores[node * NB + (tile << 6) + t] = ssum;
    }
}

__global__ __launch_bounds__(512, 4)
void score_v10_kernel(const uint4* __restrict__ a0, const uint4* __restrict__ a1,
                      const uint4* __restrict__ a2, const uint4* __restrict__ a3,
                      const uint4* __restrict__ a4, const uint4* __restrict__ a5,
                      const float* __restrict__ bias, const float* __restrict__ hvec,
                      const uint4* __restrict__ Wt, float* __restrict__ scores) {
    __shared__ uint4 lA[4096];        // 64 KB
    __shared__ float red[8 * 64];     // 2 KB
    int bid = blockIdx.x;
    int node = bid % 6;
    int tile = bid / 6;
    switch (node) {
        case 0: score_v10_body<1024>(a0, 0, tile, bias, hvec, Wt, scores, lA, red); break;
        case 1: score_v10_body<512>(a1, 1, tile, bias, hvec, Wt, scores, lA, red); break;
        case 2: score_v10_body<512>(a2, 2, tile, bias, hvec, Wt, scores, lA, red); break;
        case 3: score_v10_body<512>(a3, 3, tile, bias, hvec, Wt, scores, lA, red); break;
        case 4: score_v10_body<1024>(a4, 4, tile, bias, hvec, Wt, scores, lA, red); break;
        default: score_v10_body<512>(a5, 5, tile, bias, hvec, Wt, scores, lA, red); break;
    }
}

// ---------------------------------------------------------------------------
// Fallback score (round-8 kernel, used only if ws_size too small).
// ---------------------------------------------------------------------------
template<int MFN, int DN>
__device__ __forceinline__ void fb_score_body(
        const float* __restrict__ xp, int node, int m0,
        const float* __restrict__ bias, const float* __restrict__ hvec,
        const uint4* __restrict__ Wt, float* __restrict__ scores,
        uint4* lA, float* red) {
    constexpr int BM = MFN * 16;
    constexpr int NKB = DN / 32;
    int t = threadIdx.x;
    int l = t & 63;
    int w = t >> 6;
#pragma unroll
    for (int j = 0; j < 16; ++j) {
        int f = (t >> 6) + j * 8;
        int kb = f / MFN, mf = f % MFN;
        int row = mf * 16 + (l & 15);
        int k = kb * 32 + ((l >> 4) << 3);
        const float* g = xp + (size_t)(m0 + row) * DN + k;
        lA[f * 64 + l] = pack8(*(const float4*)g, *(const float4*)(g + 4));
    }
    __syncthreads();
    f32x4 acc[MFN][4];
#pragma unroll
    for (int mf = 0; mf < MFN; ++mf)
#pragma unroll
        for (int nf = 0; nf < 4; ++nf)
            acc[mf][nf] = (f32x4){0.f, 0.f, 0.f, 0.f};
    for (int kb = 0; kb < NKB; ++kb) {
        bf16x8 bfr[4];
        const uint4* wp = Wt + (((kb << 5) + (w << 2)) << 6) + l;
#pragma unroll
        for (int nf = 0; nf < 4; ++nf) {
            uint4 u = wp[nf << 6];
            __builtin_memcpy(&bfr[nf], &u, 16);
        }
#pragma unroll
        for (int mf = 0; mf < MFN; ++mf) {
            uint4 u = lA[(kb * MFN + mf) * 64 + l];
            bf16x8 afr;
            __builtin_memcpy(&afr, &u, 16);
#pragma unroll
            for (int nf = 0; nf < 4; ++nf)
                acc[mf][nf] = __builtin_amdgcn_mfma_f32_16x16x32_bf16(
                    afr, bfr[nf], acc[mf][nf], 0, 0, 0);
        }
    }
    float bv[4], hv[4];
#pragma unroll
    for (int nf = 0; nf < 4; ++nf) {
        int o = (w << 6) + (nf << 4) + (l & 15);
        bv[nf] = bias[o];
        hv[nf] = hvec[o];
    }
#pragma unroll
    for (int mf = 0; mf < MFN; ++mf) {
        float sc[4] = {0.f, 0.f, 0.f, 0.f};
#pragma unroll
        for (int nf = 0; nf < 4; ++nf)
#pragma unroll
            for (int r = 0; r < 4; ++r) {
                float xv = acc[mf][nf][r] + bv[nf];
                float th = 1.f - 2.f * __builtin_amdgcn_rcpf(1.f + __expf(2.f * xv));
                sc[r] = fmaf(hv[nf], th, sc[r]);
            }
#pragma unroll
        for (int r = 0; r < 4; ++r) {
            float v = sc[r];
            v += __shfl_xor(v, 1);
            v += __shfl_xor(v, 2);
            v += __shfl_xor(v, 4);
            v += __shfl_xor(v, 8);
            if ((l & 15) == 0)
                red[w * BM + (mf << 4) + ((l >> 4) << 2) + r] = v;
        }
    }
    __syncthreads();
    if (t < BM) {
        float ssum = 0.f;
#pragma unroll
        for (int w2 = 0; w2 < 8; ++w2) ssum += red[w2 * BM + t];
        scores[node * NB + m0 + t] = ssum;
    }
}

__global__ __launch_bounds__(512, 2)
void fb_score_kernel(const float* __restrict__ x0, const float* __restrict__ x1,
                     const float* __restrict__ x2, const float* __restrict__ x3,
                     const float* __restrict__ x4, const float* __restrict__ x5,
                     const float* __restrict__ bias, const float* __restrict__ hvec,
                     const uint4* __restrict__ Wt, float* __restrict__ scores) {
    __shared__ uint4 lA[8192];
    __shared__ float red[8 * 128];
    int bid = blockIdx.x;
    if (bid < 256) {
        const float* xp = (bid & 1) ? x4 : x0;
        int node = (bid & 1) ? 4 : 0;
        int m0 = (bid >> 1) * 64;
        fb_score_body<4, 1024>(xp, node, m0, bias, hvec, Wt, scores, lA, red);
    } else {
        int lb = bid - 256;
        int ni = lb & 3;
        const float* xp = (ni == 0) ? x1 : (ni == 1) ? x2 : (ni == 2) ? x3 : x5;
        int node = (ni == 0) ? 1 : (ni == 1) ? 2 : (ni == 2) ? 3 : 5;
        int m0 = (lb >> 2) * 128;
        fb_score_body<8, 512>(xp, node, m0, bias, hvec, Wt, scores, lA, red);
    }
}

// ---------------------------------------------------------------------------
// z kernel (unchanged)
// ---------------------------------------------------------------------------
__global__ __launch_bounds__(256)
void z_kernel(const float* __restrict__ x0, const float* __restrict__ x1,
              const float* __restrict__ x2, const float* __restrict__ x3,
              const float* __restrict__ x4, const float* __restrict__ x5,
              const float* __restrict__ scores, float* __restrict__ out) {
    int wv = threadIdx.x >> 6;
    int lane = threadIdx.x & 63;
    int b = (blockIdx.x << 2) + wv;

    float s0 = scores[b];
    float s1 = scores[NB + b];
    float s2 = scores[2 * NB + b];
    float s3 = scores[3 * NB + b];
    float s4 = scores[4 * NB + b];
    float s5 = scores[5 * NB + b];
    float m = fmaxf(fmaxf(fmaxf(s0, s1), fmaxf(s2, s3)), fmaxf(s4, s5));
    float e0 = __expf(s0 - m), e1 = __expf(s1 - m), e2 = __expf(s2 - m);
    float e3 = __expf(s3 - m), e4 = __expf(s4 - m), e5 = __expf(s5 - m);
    float inv = __builtin_amdgcn_rcpf(e0 + e1 + e2 + e3 + e4 + e5);
    float b0 = e0 * inv, b1 = e1 * inv, b2 = e2 * inv;
    float b3 = e3 * inv, b4 = e4 * inv, b5 = e5 * inv;

    const float* pls = x0 + (size_t)b * 1024;
    const float* pA  = x1 + (size_t)b * 512;
    const float* plm = x2 + (size_t)b * 512;
    const float* pAT = x3 + (size_t)b * 512;
    const float* pds = x4 + (size_t)b * 1024;
    const float* pdm = x5 + (size_t)b * 512;
    float* po = out + (size_t)b * 2048;

#pragma unroll
    for (int j = 0; j < 2; ++j) {
        int c = (j << 8) + (lane << 2);
        float4 vls = *(const float4*)(pls + c);
        float4 vA  = *(const float4*)(pA + c);
        float4 vlm = *(const float4*)(plm + c);
        float4 vAT = *(const float4*)(pAT + c);
        float4 vds = *(const float4*)(pds + c);
        float4 vdm = *(const float4*)(pdm + c);
        float4 r;
        r.x = b0*vls.x + b1*vA.x + b2*vlm.x + b3*vAT.x + b4*vds.x + b5*vdm.x;
        r.y = b0*vls.y + b1*vA.y + b2*vlm.y + b3*vAT.y + b4*vds.y + b5*vdm.y;
        r.z = b0*vls.z + b1*vA.z + b2*vlm.z + b3*vAT.z + b4*vds.z + b5*vdm.z;
        r.w = b0*vls.w + b1*vA.w + b2*vlm.w + b3*vAT.w + b4*vds.w + b5*vdm.w;
        *(float4*)(po + c) = r;
    }
#pragma unroll
    for (int j = 0; j < 2; ++j) {
        int c = 512 + (j << 8) + (lane << 2);
        float4 vls = *(const float4*)(pls + c);
        float4 vds = *(const float4*)(pds + c);
        float4 r;
        r.x = b0*vls.x + b4*vds.x;
        r.y = b0*vls.y + b4*vds.y;
        r.z = b0*vls.z + b4*vds.z;
        r.w = b0*vls.w + b4*vds.w;
        *(float4*)(po + c) = r;
    }
    float4 zz = make_float4(0.f, 0.f, 0.f, 0.f);
#pragma unroll
    for (int j = 0; j < 4; ++j) {
        int c = 1024 + (j << 8) + (lane << 2);
        *(float4*)(po + c) = zz;
    }
}

extern "C" void kernel_launch(void* const* d_in, const int* in_sizes, int n_in,
                              void* d_out, int out_size, void* d_ws, size_t ws_size,
                              hipStream_t stream) {
    const float* x0   = (const float*)d_in[0];  // ls  [8192,1024]
    const float* x1   = (const float*)d_in[1];  // A   [8192,512]
    const float* x2   = (const float*)d_in[2];  // lm  [8192,512]
    const float* x3   = (const float*)d_in[3];  // AT  [8192,512]
    const float* x4   = (const float*)d_in[4];  // ds  [8192,1024]
    const float* x5   = (const float*)d_in[5];  // dm  [8192,512]
    const float* W    = (const float*)d_in[6];  // [512,2048]
    const float* bias = (const float*)d_in[7];  // [512]
    const float* hvec = (const float*)d_in[8];  // [512,1]

    uint4* Wt = (uint4*)d_ws;                              // [0, 1MB)
    float* scores = (float*)((char*)d_ws + (1u << 20));    // [1MB, 1.2MB)
    uint4* A = (uint4*)((char*)d_ws + (2u << 20));         // [2MB, 66MB)
    size_t need = (size_t)(2u << 20) + ((size_t)64 << 20);

    prep_w_kernel<<<256, 256, 0, stream>>>(W, Wt);
    if (ws_size >= need) {
        prep_a_kernel<<<16384, 256, 0, stream>>>(x0, x1, x2, x3, x4, x5, A);
        const uint4* a0 = A;                       // 1M chunks
        const uint4* a1 = A + (2u << 19);
        const uint4* a2 = A + (3u << 19);
        const uint4* a3 = A + (4u << 19);
        const uint4* a4 = A + (5u << 19);          // 1M chunks
        const uint4* a5 = A + (7u << 19);
        score_v10_kernel<<<768, 512, 0, stream>>>(a0, a1, a2, a3, a4, a5,
                                                  bias, hvec, Wt, scores);
    } else {
        fb_score_kernel<<<512, 512, 0, stream>>>(x0, x1, x2, x3, x4, x5,
                                                 bias, hvec, Wt, scores);
    }
    z_kernel<<<2048, 256, 0, stream>>>(x0, x1, x2, x3, x4, x5, scores, (float*)d_out);
}

// Round 11
// 114.105 us; speedup vs baseline: 1.6417x; 1.1510x over previous
//
#include <hip/hip_runtime.h>
#include <hip/hip_bf16.h>
#include <stdint.h>

typedef __attribute__((ext_vector_type(8))) short bf16x8;
typedef __attribute__((ext_vector_type(4))) float f32x4;

#define NB 8192

__device__ __forceinline__ unsigned pkbf(float x, float y) {
    __hip_bfloat162 h = __float22bfloat162_rn(make_float2(x, y));  // v_cvt_pk_bf16_f32 (RNE)
    unsigned r;
    __builtin_memcpy(&r, &h, 4);
    return r;
}

__device__ __forceinline__ uint4 pack8(float4 a, float4 b) {
    uint4 r;
    r.x = pkbf(a.x, a.y);
    r.y = pkbf(a.z, a.w);
    r.z = pkbf(b.x, b.y);
    r.w = pkbf(b.z, b.w);
    return r;
}

// ---------------------------------------------------------------------------
// prep_w: W[512][2048] fp32 -> bf16 fragment-linear (B operand). Unchanged.
// Fragment (kb,cb): uint4 index (kb*32+cb)*64 + lane;
// elem j = W[cb*16 + (lane&15)][kb*32 + (lane>>4)*8 + j]
// ---------------------------------------------------------------------------
__global__ __launch_bounds__(256)
void prep_w_kernel(const float* __restrict__ W, uint4* __restrict__ Wt) {
    int t = blockIdx.x * 256 + threadIdx.x;
    int lane = t & 63;
    int frag = t >> 6;
    int kb = frag >> 5, cb = frag & 31;
    int o = cb * 16 + (lane & 15);
    int k = kb * 32 + ((lane >> 4) << 3);
    const float* src = W + (size_t)o * 2048 + k;
    Wt[t] = pack8(*(const float4*)src, *(const float4*)(src + 4));
}

// ---------------------------------------------------------------------------
// score v11: 768 blocks x 512 thr (8 waves). node=bid%6, tile=bid/6, BM=64,
// BN=512 (wave w: cols [w*64,+64)), acc[4][4] = 64 AGPR.
//
// THE r1-r10 DISEASE (diagnosed from r9 ablation algebra + r10 occupancy):
// every variant ran 1 block/CU (VGPR+AGPR > 128 -> 2 waves/SIMD) with all 8
// waves executing the IDENTICAL instruction stream from the same barrier ->
// their memory stalls COINCIDE, so co-resident waves hide nothing (convoy).
// v11 desyncs the waves two ways:
//   1. k-STAGGER: wave w computes kbh in rotated order (start at 2w) --
//      accumulation order is sum-invariant; B/LDS accesses now interleave.
//   2. depth-2 register prefetch of B and A fragments (static parity idx),
//      fully unrolled 16-iter compute loop per k-half.
// A staged directly from fp32 x (prep_a dropped: its 192MB extra traffic
// cost 40us to save 19). LDS = single 64KB k-half + 2KB red; 3 barriers
// per heavy block (1 per light).
// ---------------------------------------------------------------------------
template<int DN>
__device__ __forceinline__ void score_body(
        const float* __restrict__ xp, int node, int tile,
        const float* __restrict__ bias, const float* __restrict__ hvec,
        const uint4* __restrict__ Wt, float* __restrict__ scores,
        uint4* lA, float* red) {
    constexpr int NKH = DN / 512;      // k-halves: 2 heavy, 1 light
    int t = threadIdx.x;
    int l = t & 63;
    int w = t >> 6;
    int m0 = tile << 6;

    f32x4 acc[4][4];
#pragma unroll
    for (int mf = 0; mf < 4; ++mf)
#pragma unroll
        for (int nf = 0; nf < 4; ++nf)
            acc[mf][nf] = (f32x4){0.f, 0.f, 0.f, 0.f};

    for (int kh = 0; kh < NKH; ++kh) {
        if (kh > 0) __syncthreads();       // all waves done reading lA
        // ---- stage k-half: 64 rows x 512 k fp32 -> bf16 frag-linear ----
#pragma unroll
        for (int j = 0; j < 8; ++j) {
            int f = (t >> 6) + (j << 3);   // frag 0..63: kbh=f>>2, mf=f&3
            int row = (f & 3) * 16 + (l & 15);
            int k = (kh << 9) + ((f >> 2) << 5) + ((l >> 4) << 3);
            const float* g = xp + (size_t)(m0 + row) * DN + k;
            lA[(f << 6) + l] = pack8(*(const float4*)g, *(const float4*)(g + 4));
        }
        __syncthreads();

        // ---- staggered, depth-2-pipelined compute over 16 kbh ----
        int kbh0 = w << 1;                 // wave-specific rotation
        uint4 bB[2][4], aA[2][4];
        {
            int kbh = kbh0 & 15;
            const uint4* wp = Wt + ((((kh << 4) + kbh) * 32 + (w << 2)) << 6) + l;
#pragma unroll
            for (int nf = 0; nf < 4; ++nf) bB[0][nf] = wp[nf << 6];
#pragma unroll
            for (int mf = 0; mf < 4; ++mf) aA[0][mf] = lA[(((kbh << 2) + mf) << 6) + l];
        }
#pragma unroll
        for (int i = 0; i < 16; ++i) {
            int cur = i & 1, nxt = cur ^ 1;
            if (i < 15) {
                int kbh = (kbh0 + i + 1) & 15;
                const uint4* wp = Wt + ((((kh << 4) + kbh) * 32 + (w << 2)) << 6) + l;
#pragma unroll
                for (int nf = 0; nf < 4; ++nf) bB[nxt][nf] = wp[nf << 6];
#pragma unroll
                for (int mf = 0; mf < 4; ++mf) aA[nxt][mf] = lA[(((kbh << 2) + mf) << 6) + l];
            }
#pragma unroll
            for (int mf = 0; mf < 4; ++mf) {
                bf16x8 afr;
                __builtin_memcpy(&afr, &aA[cur][mf], 16);
#pragma unroll
                for (int nf = 0; nf < 4; ++nf) {
                    bf16x8 bfr;
                    __builtin_memcpy(&bfr, &bB[cur][nf], 16);
                    acc[mf][nf] = __builtin_amdgcn_mfma_f32_16x16x32_bf16(
                        afr, bfr, acc[mf][nf], 0, 0, 0);
                }
            }
        }
    }

    // ---- epilogue: tanh, dot with h, reduce to per-row score ----
    float bv[4], hv[4];
#pragma unroll
    for (int nf = 0; nf < 4; ++nf) {
        int o = (w << 6) + (nf << 4) + (l & 15);
        bv[nf] = bias[o];
        hv[nf] = hvec[o];
    }
#pragma unroll
    for (int mf = 0; mf < 4; ++mf) {
        float sc[4] = {0.f, 0.f, 0.f, 0.f};
#pragma unroll
        for (int nf = 0; nf < 4; ++nf) {
#pragma unroll
            for (int r = 0; r < 4; ++r) {
                float xv = acc[mf][nf][r] + bv[nf];
                float th = 1.f - 2.f * __builtin_amdgcn_rcpf(1.f + __expf(2.f * xv));
                sc[r] = fmaf(hv[nf], th, sc[r]);
            }
        }
#pragma unroll
        for (int r = 0; r < 4; ++r) {
            float v = sc[r];
            v += __shfl_xor(v, 1);
            v += __shfl_xor(v, 2);
            v += __shfl_xor(v, 4);
            v += __shfl_xor(v, 8);
            if ((l & 15) == 0)
                red[(w << 6) + (mf << 4) + ((l >> 4) << 2) + r] = v;
        }
    }
    __syncthreads();
    if (t < 64) {
        float ssum = 0.f;
#pragma unroll
        for (int w2 = 0; w2 < 8; ++w2) ssum += red[(w2 << 6) + t];
        scores[node * NB + m0 + t] = ssum;
    }
}

__global__ __launch_bounds__(512)
void score_kernel(const float* __restrict__ x0, const float* __restrict__ x1,
                  const float* __restrict__ x2, const float* __restrict__ x3,
                  const float* __restrict__ x4, const float* __restrict__ x5,
                  const float* __restrict__ bias, const float* __restrict__ hvec,
                  const uint4* __restrict__ Wt, float* __restrict__ scores) {
    __shared__ uint4 lA[4096];        // 64 KB k-half
    __shared__ float red[8 * 64];     // 2 KB
    int bid = blockIdx.x;
    int node = bid % 6;
    int tile = bid / 6;
    switch (node) {
        case 0: score_body<1024>(x0, 0, tile, bias, hvec, Wt, scores, lA, red); break;
        case 1: score_body<512>(x1, 1, tile, bias, hvec, Wt, scores, lA, red); break;
        case 2: score_body<512>(x2, 2, tile, bias, hvec, Wt, scores, lA, red); break;
        case 3: score_body<512>(x3, 3, tile, bias, hvec, Wt, scores, lA, red); break;
        case 4: score_body<1024>(x4, 4, tile, bias, hvec, Wt, scores, lA, red); break;
        default: score_body<512>(x5, 5, tile, bias, hvec, Wt, scores, lA, red); break;
    }
}

// ---------------------------------------------------------------------------
// z kernel: one wave per batch. softmax over 6 scores, then
// z[0:512]=sum beta_n x_n ; z[512:1024]=b0*ls+b4*ds ; z[1024:2048]=0
// ---------------------------------------------------------------------------
__global__ __launch_bounds__(256)
void z_kernel(const float* __restrict__ x0, const float* __restrict__ x1,
              const float* __restrict__ x2, const float* __restrict__ x3,
              const float* __restrict__ x4, const float* __restrict__ x5,
              const float* __restrict__ scores, float* __restrict__ out) {
    int wv = threadIdx.x >> 6;
    int lane = threadIdx.x & 63;
    int b = (blockIdx.x << 2) + wv;

    float s0 = scores[b];
    float s1 = scores[NB + b];
    float s2 = scores[2 * NB + b];
    float s3 = scores[3 * NB + b];
    float s4 = scores[4 * NB + b];
    float s5 = scores[5 * NB + b];
    float m = fmaxf(fmaxf(fmaxf(s0, s1), fmaxf(s2, s3)), fmaxf(s4, s5));
    float e0 = __expf(s0 - m), e1 = __expf(s1 - m), e2 = __expf(s2 - m);
    float e3 = __expf(s3 - m), e4 = __expf(s4 - m), e5 = __expf(s5 - m);
    float inv = __builtin_amdgcn_rcpf(e0 + e1 + e2 + e3 + e4 + e5);
    float b0 = e0 * inv, b1 = e1 * inv, b2 = e2 * inv;
    float b3 = e3 * inv, b4 = e4 * inv, b5 = e5 * inv;

    const float* pls = x0 + (size_t)b * 1024;
    const float* pA  = x1 + (size_t)b * 512;
    const float* plm = x2 + (size_t)b * 512;
    const float* pAT = x3 + (size_t)b * 512;
    const float* pds = x4 + (size_t)b * 1024;
    const float* pdm = x5 + (size_t)b * 512;
    float* po = out + (size_t)b * 2048;

#pragma unroll
    for (int j = 0; j < 2; ++j) {
        int c = (j << 8) + (lane << 2);
        float4 vls = *(const float4*)(pls + c);
        float4 vA  = *(const float4*)(pA + c);
        float4 vlm = *(const float4*)(plm + c);
        float4 vAT = *(const float4*)(pAT + c);
        float4 vds = *(const float4*)(pds + c);
        float4 vdm = *(const float4*)(pdm + c);
        float4 r;
        r.x = b0*vls.x + b1*vA.x + b2*vlm.x + b3*vAT.x + b4*vds.x + b5*vdm.x;
        r.y = b0*vls.y + b1*vA.y + b2*vlm.y + b3*vAT.y + b4*vds.y + b5*vdm.y;
        r.z = b0*vls.z + b1*vA.z + b2*vlm.z + b3*vAT.z + b4*vds.z + b5*vdm.z;
        r.w = b0*vls.w + b1*vA.w + b2*vlm.w + b3*vAT.w + b4*vds.w + b5*vdm.w;
        *(float4*)(po + c) = r;
    }
#pragma unroll
    for (int j = 0; j < 2; ++j) {
        int c = 512 + (j << 8) + (lane << 2);
        float4 vls = *(const float4*)(pls + c);
        float4 vds = *(const float4*)(pds + c);
        float4 r;
        r.x = b0*vls.x + b4*vds.x;
        r.y = b0*vls.y + b4*vds.y;
        r.z = b0*vls.z + b4*vds.z;
        r.w = b0*vls.w + b4*vds.w;
        *(float4*)(po + c) = r;
    }
    float4 zz = make_float4(0.f, 0.f, 0.f, 0.f);
#pragma unroll
    for (int j = 0; j < 4; ++j) {
        int c = 1024 + (j << 8) + (lane << 2);
        *(float4*)(po + c) = zz;
    }
}

extern "C" void kernel_launch(void* const* d_in, const int* in_sizes, int n_in,
                              void* d_out, int out_size, void* d_ws, size_t ws_size,
                              hipStream_t stream) {
    const float* x0   = (const float*)d_in[0];  // ls  [8192,1024]
    const float* x1   = (const float*)d_in[1];  // A   [8192,512]
    const float* x2   = (const float*)d_in[2];  // lm  [8192,512]
    const float* x3   = (const float*)d_in[3];  // AT  [8192,512]
    const float* x4   = (const float*)d_in[4];  // ds  [8192,1024]
    const float* x5   = (const float*)d_in[5];  // dm  [8192,512]
    const float* W    = (const float*)d_in[6];  // [512,2048]
    const float* bias = (const float*)d_in[7];  // [512]
    const float* hvec = (const float*)d_in[8];  // [512,1]

    uint4* Wt = (uint4*)d_ws;                              // 1 MB
    float* scores = (float*)((char*)d_ws + (1u << 20));    // 192 KB

    prep_w_kernel<<<256, 256, 0, stream>>>(W, Wt);
    score_kernel<<<768, 512, 0, stream>>>(x0, x1, x2, x3, x4, x5, bias, hvec, Wt, scores);
    z_kernel<<<2048, 256, 0, stream>>>(x0, x1, x2, x3, x4, x5, scores, (float*)d_out);
}